// Round 3
// baseline (16912.846 us; speedup 1.0000x reference)
//
#include <hip/hip_runtime.h>

typedef unsigned short u16;
typedef unsigned int u32;
typedef unsigned long long u64;
typedef __attribute__((ext_vector_type(8))) short short8;
typedef __attribute__((ext_vector_type(4))) float f32x4;

#define T_STEPS 512
#define HF_OFF 50331648UL
#define NWG 128

__device__ __forceinline__ u16 f2bf(float f) {
  union { float f; unsigned u; } v; v.f = f;
  unsigned r = (v.u + 0x7FFFu + ((v.u >> 16) & 1u)) >> 16;
  return (u16)r;
}

__device__ __forceinline__ short8 pack8(float4 f0, float4 f1) {
  short8 v;
  v[0]=(short)f2bf(f0.x); v[1]=(short)f2bf(f0.y); v[2]=(short)f2bf(f0.z); v[3]=(short)f2bf(f0.w);
  v[4]=(short)f2bf(f1.x); v[5]=(short)f2bf(f1.y); v[6]=(short)f2bf(f1.z); v[7]=(short)f2bf(f1.w);
  return v;
}

__device__ __forceinline__ float sigm(float x) { return 1.0f / (1.0f + __expf(-x)); }
__device__ __forceinline__ float tanh_f(float x) { return 1.0f - 2.0f / (__expf(2.0f * x) + 1.0f); }

// Build Wr[l][j*4+g][k] (bf16, K-major, k<768 from W_ih, k>=768 from W_hh),
// rows permuted so gate cols for h-column j are contiguous (i,f,g,o interleave).
__global__ void prep_weights(const float* __restrict__ Wih, const float* __restrict__ Whh,
                             u16* __restrict__ Wr) {
  int idx = blockIdx.x * blockDim.x + threadIdx.x;
  if (idx >= 2 * 3072 * 192) return;
  int r = idx / 192;
  int kc = (idx - r * 192) * 8;
  int l = r / 3072;
  int rr = r - l * 3072;
  int j = rr >> 2, g = rr & 3;
  int srow = l * 3072 + g * 768 + j;
  const float* src = (kc < 768) ? (Wih + (size_t)srow * 768 + kc)
                                : (Whh + (size_t)srow * 768 + (kc - 768));
  float4 f0 = *(const float4*)src;
  float4 f1 = *(const float4*)(src + 4);
  *(short8*)(Wr + (size_t)r * 1536 + kc) = pack8(f0, f1);
}

// bcat[l][j*4+g] = b_ih + b_hh (same permutation); hbuf[l][1] = bf16(h0[l]);
// zero the barrier slots/flag.
__global__ void prep_misc(const float* __restrict__ h0, const float* __restrict__ bih,
                          const float* __restrict__ bhh, u16* __restrict__ hbuf,
                          float* __restrict__ bcat, int* __restrict__ bar) {
  int idx = blockIdx.x * blockDim.x + threadIdx.x;
  if (idx < 512) bar[idx] = 0;
  if (idx < 6144) {
    int l = idx / 3072;
    int rr = idx - l * 3072;
    int j = rr >> 2, g = rr & 3;
    int s = l * 3072 + g * 768 + j;
    bcat[idx] = bih[s] + bhh[s];
  }
  int hi = idx - 6144;
  if (hi >= 0 && hi < 98304) {
    int l = hi / 49152;
    int bj = hi - l * 49152;
    hbuf[(size_t)(l * 2 + 1) * 49152 + bj] = f2bf(h0[hi]);
  }
}

// Persistent kernel: 128 WGs (wg>>6 = layer, wg&63 = wgi owning h-cols [wgi*12, +12)).
// Wavefront s: layer0 does t=s, layer1 does t=s-1; one flag-barrier per wavefront.
__global__ void __launch_bounds__(256, 2)
lstm_persistent(const float* __restrict__ x, const float* __restrict__ h0,
                const float* __restrict__ c0, const int* __restrict__ len,
                const u16* __restrict__ Wr, const float* __restrict__ bcat,
                u16* __restrict__ hbuf, float* __restrict__ out,
                int* __restrict__ bar) {
  __shared__ u16 lA[64 * 256];     // A chunk  [64][256] bf16, swizzled
  __shared__ u16 lW[48 * 256];     // W chunk  [48][256] bf16, swizzled
  __shared__ float lG[4][16 * 48]; // per-wave gate staging
  __shared__ u16 lH[4][192];       // per-wave h writeback bounce (16 rows x 12 cols)
  __shared__ float lBias[48];
  __shared__ int lLen[64];

  const int tid = threadIdx.x;
  const int wv = tid >> 6;
  const int ln = tid & 63;
  const int wg = blockIdx.x;
  const int layer = wg >> 6;
  const int wgi = wg & 63;
  const int n0 = wgi * 48;   // gate-col base (permuted rows of Wr)
  const int j0 = wgi * 12;   // h-col base

  int* slots = bar;          // [128] per-WG arrival step numbers
  int* flagp = bar + 256;    // global release flag

  if (tid < 48) lBias[tid] = bcat[layer * 3072 + n0 + tid];
  if (tid < 64) lLen[tid] = len[tid];

  // Each thread owns 3 (b, j) state cells: p = ln*3+e -> (bl = p/12, jj = p%12)
  int bl[3], jj[3];
  float cReg[3], hKeep[3];
#pragma unroll
  for (int e = 0; e < 3; ++e) {
    int p = ln * 3 + e;
    bl[e] = p / 12;
    jj[e] = p % 12;
    int b = wv * 16 + bl[e];
    int j = j0 + jj[e];
    cReg[e] = c0[(size_t)(layer * 64 + b) * 768 + j];
    hKeep[e] = h0[(size_t)(layer * 64 + b) * 768 + j];
  }
  __syncthreads();

  for (int s = 0; s <= T_STEPS; ++s) {
    const int t = (layer == 0) ? s : s - 1;
    if (t >= 0 && t < T_STEPS) {
      const u16* hprev = hbuf + (size_t)(layer * 2 + ((t - 1) & 1)) * 49152;
      const u16* h0cur = hbuf + (size_t)(t & 1) * 49152;  // layer1 low-K source
      u16* hout = hbuf + (size_t)(layer * 2 + (t & 1)) * 49152;

      f32x4 acc[3] = {};

      for (int ck = 0; ck < 6; ++ck) {
        const int koff = ck * 256;
        // ---- stage A [64][256] ----
        if (layer == 0 && ck < 3) {
          const float* src = x + (size_t)t * 49152 + koff;
#pragma unroll
          for (int it = tid; it < 2048; it += 256) {
            int row = it >> 5;
            int kk = (it & 31) << 3;
            const float* p = src + row * 768 + kk;
            float4 f0 = *(const float4*)p;
            float4 f1 = *(const float4*)(p + 4);
            *(short8*)&lA[row * 256 + (kk ^ ((row & 7) << 3))] = pack8(f0, f1);
          }
        } else {
          // h sources: agent-scope u64 loads (coherent via L3, L2 stays clean)
          const u64* src64 = (const u64*)((ck < 3) ? (h0cur + koff) : (hprev + (koff - 768)));
#pragma unroll
          for (int it = tid; it < 4096; it += 256) {
            int row = it >> 6;
            int kk4 = (it & 63) << 2;  // u16 index in chunk, 4-aligned
            u64 v = __hip_atomic_load(src64 + row * 192 + (kk4 >> 2),
                                      __ATOMIC_RELAXED, __HIP_MEMORY_SCOPE_AGENT);
            *(u64*)&lA[row * 256 + (kk4 ^ ((row & 7) << 3))] = v;
          }
        }
        // ---- stage W [48][256] (normal loads, stays L2-resident) ----
        {
          const u16* srcW = Wr + (size_t)(layer * 3072 + n0) * 1536 + koff;
#pragma unroll
          for (int it = tid; it < 1536; it += 256) {
            int row = it >> 5;
            int kk = (it & 31) << 3;
            short8 v = *(const short8*)(srcW + (size_t)row * 1536 + kk);
            *(short8*)&lW[row * 256 + (kk ^ ((row & 7) << 3))] = v;
          }
        }
        __syncthreads();

        // ---- MFMA: wave wv owns rows [16wv,16wv+16), all 48 cols ----
        const int arow = wv * 16 + (ln & 15);
        const int kb = (ln >> 4) << 3;
        const int aswz = (arow & 7) << 3;
#pragma unroll
        for (int kk = 0; kk < 8; ++kk) {
          const int k = kk * 32 + kb;
          short8 a = *(const short8*)&lA[arow * 256 + (k ^ aswz)];
#pragma unroll
          for (int ct = 0; ct < 3; ++ct) {
            const int nrow = ct * 16 + (ln & 15);
            short8 b = *(const short8*)&lW[nrow * 256 + (k ^ ((nrow & 7) << 3))];
            acc[ct] = __builtin_amdgcn_mfma_f32_16x16x32_bf16(a, b, acc[ct], 0, 0, 0);
          }
        }
        __syncthreads();
      }

      // ---- gates -> LDS (per-wave region; reader is the same wave) ----
      {
        const int c0l = ln & 15;
        const int r0 = (ln >> 4) << 2;
#pragma unroll
        for (int ct = 0; ct < 3; ++ct)
#pragma unroll
          for (int r = 0; r < 4; ++r)
            lG[wv][(r0 + r) * 48 + ct * 16 + c0l] = acc[ct][r];
      }
      asm volatile("s_waitcnt lgkmcnt(0)" ::: "memory");

      // ---- pointwise LSTM cell + mask ----
#pragma unroll
      for (int e = 0; e < 3; ++e) {
        const int b = wv * 16 + bl[e];
        const int jloc = jj[e];
        const float4 g4 = *(const float4*)&lG[wv][bl[e] * 48 + jloc * 4];
        const float4 bb = *(const float4*)&lBias[jloc * 4];
        float gi = g4.x + bb.x;
        float gf = g4.y + bb.y;
        float gg = g4.z + bb.z;
        float go = g4.w + bb.w;
        float cn = sigm(gf) * cReg[e] + sigm(gi) * tanh_f(gg);
        float hn = sigm(go) * tanh_f(cn);
        const bool act = t < lLen[b];
        const float hm = act ? hn : hKeep[e];
        const float cm = act ? cn : cReg[e];
        hKeep[e] = hm;
        cReg[e] = cm;
        const int j = j0 + jloc;
        out[((size_t)(t * 64 + b) * 2 + layer) * 768 + j] = hm;
        lH[wv][bl[e] * 12 + jloc] = f2bf(hm);
      }
      asm volatile("s_waitcnt lgkmcnt(0)" ::: "memory");

      // ---- h writeback: contiguous agent-scope u32 stores (bypass L2) ----
#pragma unroll
      for (int it = ln; it < 96; it += 64) {
        int b = it / 6, w = it - b * 6;
        u32 val = *(const u32*)&lH[wv][b * 12 + 2 * w];
        u32* dst = (u32*)(hout + (size_t)(wv * 16 + b) * 768 + j0) + w;
        __hip_atomic_store(dst, val, __ATOMIC_RELAXED, __HIP_MEMORY_SCOPE_AGENT);
      }
    }

    // ---- flag barrier: plain stores + collector, no RMW, no cache flush ----
    __syncthreads();  // drains each wave's vmcnt -> h stores at coherence point
    const int target = s + 1;
    if (tid == 0) {
      __hip_atomic_store(&slots[wg], target, __ATOMIC_RELAXED, __HIP_MEMORY_SCOPE_AGENT);
    }
    if (wg == 0) {
      if (wv == 0) {
        for (;;) {
          int a = __hip_atomic_load(&slots[ln], __ATOMIC_RELAXED, __HIP_MEMORY_SCOPE_AGENT);
          int b = __hip_atomic_load(&slots[64 + ln], __ATOMIC_RELAXED, __HIP_MEMORY_SCOPE_AGENT);
          if (__all(a >= target && b >= target)) break;
          __builtin_amdgcn_s_sleep(1);
        }
        if (ln == 0) {
          __hip_atomic_store(flagp, target, __ATOMIC_RELAXED, __HIP_MEMORY_SCOPE_AGENT);
        }
      }
    } else {
      if (tid == 0) {
        while (__hip_atomic_load(flagp, __ATOMIC_RELAXED, __HIP_MEMORY_SCOPE_AGENT) < target) {
          __builtin_amdgcn_s_sleep(2);
        }
      }
    }
    __syncthreads();
    asm volatile("" ::: "memory");
  }

  // final states
  float* hf = out + HF_OFF;
  float* cf = out + HF_OFF + 98304;
#pragma unroll
  for (int e = 0; e < 3; ++e) {
    const int b = wv * 16 + bl[e];
    const int j = j0 + jj[e];
    hf[(size_t)(layer * 64 + b) * 768 + j] = hKeep[e];
    cf[(size_t)(layer * 64 + b) * 768 + j] = cReg[e];
  }
}

extern "C" void kernel_launch(void* const* d_in, const int* in_sizes, int n_in,
                              void* d_out, int out_size, void* d_ws, size_t ws_size,
                              hipStream_t stream) {
  const float* x   = (const float*)d_in[0];
  const float* h0  = (const float*)d_in[1];
  const float* c0  = (const float*)d_in[2];
  const float* Wih = (const float*)d_in[3];
  const float* Whh = (const float*)d_in[4];
  const float* bih = (const float*)d_in[5];
  const float* bhh = (const float*)d_in[6];
  const int*   len = (const int*)d_in[7];
  float* out = (float*)d_out;

  u16*   Wr   = (u16*)d_ws;                            // 2*3072*1536 bf16 = 18.87 MB
  float* bcat = (float*)((char*)d_ws + 18874368);      // 6144 f32
  u16*   hbuf = (u16*)((char*)d_ws + 18898944);        // 2 layers * 2 bufs * 64*768 bf16
  int*   bar  = (int*)((char*)d_ws + 19292160);        // arrival slots + flag

  {
    const int units = 2 * 3072 * 192;
    prep_weights<<<(units + 255) / 256, 256, 0, stream>>>(Wih, Whh, Wr);
    const int n2 = 6144 + 98304;
    prep_misc<<<(n2 + 255) / 256, 256, 0, stream>>>(h0, bih, bhh, hbuf, bcat, bar);
  }

  void* args[] = { (void*)&x, (void*)&h0, (void*)&c0, (void*)&len,
                   (void*)&Wr, (void*)&bcat, (void*)&hbuf, (void*)&out,
                   (void*)&bar };
  hipLaunchCooperativeKernel((const void*)lstm_persistent, dim3(NWG), dim3(256),
                             args, 0, stream);
}

// Round 4
// 4706.551 us; speedup vs baseline: 3.5935x; 3.5935x over previous
//
#include <hip/hip_runtime.h>

typedef unsigned short u16;
typedef unsigned int u32;
typedef unsigned long long u64;
typedef __attribute__((ext_vector_type(8))) short short8;
typedef __attribute__((ext_vector_type(4))) float f32x4;

#define T_STEPS 512
#define HF_OFF 50331648UL

// ws layout (bytes)
#define BCAT_OFF  18874368UL
#define HB0_OFF   18898944UL                  // 32 slots * 98304 u16 * 2B
#define HB1_OFF   (HB0_OFF + 32UL*98304UL)    // 4 slots
#define FLG_OFF   (HB1_OFF + 4UL*98304UL)     // flags [2][514][2][64] u32

__device__ __forceinline__ u16 f2bf(float f) {
  union { float f; unsigned u; } v; v.f = f;
  unsigned r = (v.u + 0x7FFFu + ((v.u >> 16) & 1u)) >> 16;
  return (u16)r;
}

__device__ __forceinline__ short8 pack8(float4 f0, float4 f1) {
  short8 v;
  v[0]=(short)f2bf(f0.x); v[1]=(short)f2bf(f0.y); v[2]=(short)f2bf(f0.z); v[3]=(short)f2bf(f0.w);
  v[4]=(short)f2bf(f1.x); v[5]=(short)f2bf(f1.y); v[6]=(short)f2bf(f1.z); v[7]=(short)f2bf(f1.w);
  return v;
}

__device__ __forceinline__ float sigm(float x) { return 1.0f / (1.0f + __expf(-x)); }
__device__ __forceinline__ float tanh_f(float x) { return 1.0f - 2.0f / (__expf(2.0f * x) + 1.0f); }

// uncached (L3-coherent) accessors
__device__ __forceinline__ short8 load_sc_b128(const void* p) {
  short8 r;
  asm volatile("global_load_dwordx4 %0, %1, off sc0 sc1" : "=&v"(r) : "v"((u64)p));
  return r;  // caller must s_waitcnt vmcnt(0) before use
}
__device__ __forceinline__ u32 load_sc_b32(const u32* p) {
  u32 r;
  asm volatile("global_load_dword %0, %1, off sc0 sc1\n\ts_waitcnt vmcnt(0)"
               : "=&v"(r) : "v"((u64)p) : "memory");
  return r;
}
__device__ __forceinline__ void store_sc_b32(u32* p, u32 v) {
  asm volatile("global_store_dword %0, %1, off sc0 sc1" :: "v"((u64)p), "v"(v) : "memory");
}

__device__ __forceinline__ void poll1(const u32* base, int own) {
  const int ln = threadIdx.x & 63;
  for (;;) {
    u32 f = load_sc_b32(base + ln);
    if (own >= 0 && ln == own) f = 1u;
    if (__all(f != 0)) break;
    __builtin_amdgcn_s_sleep(1);
  }
}

// Wr[l][j*4+g][k] bf16 (K-major; k<768 W_ih, k>=768 W_hh), gate-interleaved rows.
__global__ void prep_weights(const float* __restrict__ Wih, const float* __restrict__ Whh,
                             u16* __restrict__ Wr) {
  int idx = blockIdx.x * blockDim.x + threadIdx.x;
  if (idx >= 2 * 3072 * 192) return;
  int r = idx / 192;
  int kc = (idx - r * 192) * 8;
  int l = r / 3072;
  int rr = r - l * 3072;
  int j = rr >> 2, g = rr & 3;
  int srow = l * 3072 + g * 768 + j;
  const float* src = (kc < 768) ? (Wih + (size_t)srow * 768 + kc)
                                : (Whh + (size_t)srow * 768 + (kc - 768));
  float4 f0 = *(const float4*)src;
  float4 f1 = *(const float4*)(src + 4);
  *(short8*)(Wr + (size_t)r * 1536 + kc) = pack8(f0, f1);
}

// flags init (tt==0 -> 1, else 0); hb0/hb1 slot0 <- bf16(h0); bcat = b_ih+b_hh permuted.
__global__ void prep_misc(const float* __restrict__ h0, const float* __restrict__ bih,
                          const float* __restrict__ bhh, u16* __restrict__ hb0,
                          u16* __restrict__ hb1, float* __restrict__ bcat,
                          u32* __restrict__ flags) {
  int idx = blockIdx.x * blockDim.x + threadIdx.x;
  if (idx < 131584) {
    flags[idx] = (((idx >> 7) % 514) == 0) ? 1u : 0u;
  } else if (idx < 131584 + 98304) {
    int r = idx - 131584;
    int l = r / 49152, o = r - l * 49152;
    u16 v = f2bf(h0[r]);
    if (l == 0) hb0[o] = v; else hb1[o] = v;
  } else if (idx < 131584 + 98304 + 6144) {
    int q = idx - (131584 + 98304);
    int l = q / 3072, rr = q - l * 3072;
    int j = rr >> 2, g = rr & 3;
    int s = l * 3072 + g * 768 + j;
    bcat[q] = bih[s] + bhh[s];
  }
}

// 256 WGs x 512 threads: wg = layer(1b) | rg(1b) | cg(6b).
// WG output tile: rows rg*32..+32 (batch), gate-cols cg*48..+48 (h-cols cg*12..+12).
// 8 waves k-split K=1536 into 192 each; W B-frags VGPR-resident; no global barrier.
__global__ void __launch_bounds__(512, 2)
lstm_dataflow(const float* __restrict__ x, const float* __restrict__ h0,
              const float* __restrict__ c0, const int* __restrict__ len,
              const u16* __restrict__ Wr, const float* __restrict__ bcat,
              u16* __restrict__ hb0, u16* __restrict__ hb1,
              u32* __restrict__ flags, float* __restrict__ out) {
  __shared__ u16 lA[32 * 1536];      // 96KB: A rows x K, byte-swizzled ^((row&7)<<4)
  __shared__ float pP[8 * 48 * 32];  // 48KB: per-wave partials [col][bloc], swizzled
  __shared__ u16 lH[32 * 12];        // h writeback bounce

  const int tid = threadIdx.x;
  const int wv = tid >> 6;
  const int ln = tid & 63;
  const int wg = blockIdx.x;
  const int layer = wg >> 7;
  const int rg = (wg >> 6) & 1;
  const int cg = wg & 63;
  const int n0 = cg * 48;
  const int row = tid >> 4;   // ingest row 0..31
  const int uu = tid & 15;    // ingest unit base

  // ---- prologue: W fragments into registers (once) ----
  short8 bfr[3][6];
  {
    const u16* wbase = Wr + (size_t)(layer * 3072 + n0) * 1536;
#pragma unroll
    for (int ct = 0; ct < 3; ++ct)
#pragma unroll
      for (int ks = 0; ks < 6; ++ks) {
        int col = ct * 16 + (ln & 15);
        int k = wv * 192 + ks * 32 + ((ln >> 4) << 3);
        bfr[ct][ks] = *(const short8*)(wbase + (size_t)col * 1536 + k);
      }
  }
  float bc[3] = {0.f, 0.f, 0.f};
  if (wv == 0) {
#pragma unroll
    for (int ct = 0; ct < 3; ++ct)
      bc[ct] = bcat[layer * 3072 + n0 + ct * 16 + (ln & 15)];
  }
  // state cells: thread tid<384 owns (b = rg*32 + tid/12, j = cg*12 + tid%12)
  const int cellb = tid / 12, cellj = tid - (tid / 12) * 12;
  float cReg = 0.f, hKeep = 0.f; int lenB = 0;
  if (tid < 384) {
    int b = rg * 32 + cellb, j = cg * 12 + cellj;
    cReg = c0[(size_t)(layer * 64 + b) * 768 + j];
    hKeep = h0[(size_t)(layer * 64 + b) * 768 + j];
    lenB = len[b];
  }

  char* lAb = (char*)lA;

  for (int t = 0; t < T_STEPS; ++t) {
    // ================= poll + ingest =================
    if (layer == 0) {
      // x-part (no dependency): iters 0..5 cover k<768
      const float* xb = x + ((size_t)t * 64 + rg * 32 + row) * 768;
#pragma unroll
      for (int i = 0; i < 6; ++i) {
        int unit = uu + i * 16;
        int kel = (unit * 8) ^ ((row & 7) << 3);
        float4 f0 = *(const float4*)(xb + kel);
        float4 f1 = *(const float4*)(xb + kel + 4);
        *(short8*)(lAb + row * 3072 + unit * 16) = pack8(f0, f1);
      }
      poll1(flags + ((size_t)(0 * 514 + t) * 2 + rg) * 64, cg);   // own-layer prev h
      if ((t & 7) == 0 && t >= 8)                                  // amortized throttle
        poll1(flags + ((size_t)(1 * 514 + (t - 8)) * 2 + rg) * 64, -1);
      const u16* hp = hb0 + (size_t)(t & 31) * 49152 + (size_t)(rg * 32 + row) * 768;
      short8 hv[6];
#pragma unroll
      for (int i = 0; i < 6; ++i) {
        int unit = uu + (i + 6) * 16;
        int kel = (unit * 8) ^ ((row & 7) << 3);
        hv[i] = load_sc_b128(hp + (kel - 768));
      }
      __builtin_amdgcn_sched_barrier(0);
      asm volatile("s_waitcnt vmcnt(0)" ::: "memory");
      __builtin_amdgcn_sched_barrier(0);
#pragma unroll
      for (int i = 0; i < 6; ++i) {
        int unit = uu + (i + 6) * 16;
        *(short8*)(lAb + row * 3072 + unit * 16) = hv[i];
      }
    } else {
      poll1(flags + ((size_t)(0 * 514 + (t + 1)) * 2 + rg) * 64, -1);  // h0 after L0 step t
      const u16* hc = hb0 + (size_t)((t + 1) & 31) * 49152 + (size_t)(rg * 32 + row) * 768;
      short8 hv[12];
#pragma unroll
      for (int i = 0; i < 6; ++i) {
        int unit = uu + i * 16;
        int kel = (unit * 8) ^ ((row & 7) << 3);
        hv[i] = load_sc_b128(hc + kel);
      }
      poll1(flags + ((size_t)(1 * 514 + t) * 2 + rg) * 64, cg);        // own prev h1
      const u16* hp = hb1 + (size_t)(t & 3) * 49152 + (size_t)(rg * 32 + row) * 768;
#pragma unroll
      for (int i = 0; i < 6; ++i) {
        int unit = uu + (i + 6) * 16;
        int kel = (unit * 8) ^ ((row & 7) << 3);
        hv[6 + i] = load_sc_b128(hp + (kel - 768));
      }
      __builtin_amdgcn_sched_barrier(0);
      asm volatile("s_waitcnt vmcnt(0)" ::: "memory");
      __builtin_amdgcn_sched_barrier(0);
#pragma unroll
      for (int i = 0; i < 12; ++i) {
        int unit = uu + i * 16;
        *(short8*)(lAb + row * 3072 + unit * 16) = hv[i];
      }
    }
    __syncthreads();  // A ready

    // ================= MFMA (k-slice wv*192, rows 2x16, cols 3x16) =================
    f32x4 acc[2][3];
#pragma unroll
    for (int rt = 0; rt < 2; ++rt)
#pragma unroll
      for (int ct = 0; ct < 3; ++ct) {
        float b0 = (wv == 0) ? bc[ct] : 0.f;
        acc[rt][ct] = (f32x4){b0, b0, b0, b0};
      }
#pragma unroll
    for (int ks = 0; ks < 6; ++ks) {
      int kb = (wv * 192 + ks * 32 + ((ln >> 4) << 3)) * 2;
#pragma unroll
      for (int rt = 0; rt < 2; ++rt) {
        int arow = rt * 16 + (ln & 15);
        short8 a = *(const short8*)(lAb + arow * 3072 + (kb ^ ((arow & 7) << 4)));
#pragma unroll
        for (int ct = 0; ct < 3; ++ct)
          acc[rt][ct] = __builtin_amdgcn_mfma_f32_16x16x32_bf16(a, bfr[ct][ks], acc[rt][ct], 0, 0, 0);
      }
    }
    // partials -> LDS: pP[wv][col][bloc] (f32x4 over bloc, swizzled)
#pragma unroll
    for (int rt = 0; rt < 2; ++rt)
#pragma unroll
      for (int ct = 0; ct < 3; ++ct) {
        int col = ct * 16 + (ln & 15);
        int q0 = rt * 16 + ((ln >> 4) << 2);
        *(f32x4*)((char*)pP + wv * 6144 + col * 128 + ((q0 * 4) ^ ((col & 7) << 4))) = acc[rt][ct];
      }
    __syncthreads();  // partials ready

    // ================= fused reduce + pointwise =================
    if (tid < 384) {
      float g4[4];
#pragma unroll
      for (int g = 0; g < 4; ++g) {
        int col = cellj * 4 + g;
        float s = 0.f;
#pragma unroll
        for (int w = 0; w < 8; ++w)
          s += *(const float*)((const char*)pP + w * 6144 + col * 128 + ((cellb * 4) ^ ((col & 7) << 4)));
        g4[g] = s;
      }
      float cn = sigm(g4[1]) * cReg + sigm(g4[0]) * tanh_f(g4[2]);
      float hn = sigm(g4[3]) * tanh_f(cn);
      const bool act = t < lenB;
      float hm = act ? hn : hKeep;
      float cm = act ? cn : cReg;
      hKeep = hm; cReg = cm;
      int bglob = rg * 32 + cellb, j = cg * 12 + cellj;
      out[((size_t)(t * 64 + bglob) * 2 + layer) * 768 + j] = hm;
      lH[cellb * 12 + cellj] = f2bf(hm);
    }
    __syncthreads();  // lH ready

    // ================= re-emit h + flag (wave 0) =================
    if (wv == 0) {
      u16* hout = (layer == 0) ? hb0 + (size_t)((t + 1) & 31) * 49152
                               : hb1 + (size_t)((t + 1) & 3) * 49152;
      const u32* lH32 = (const u32*)lH;
#pragma unroll
      for (int it = 0; it < 3; ++it) {
        int idx = ln + it * 64;
        int r = idx / 6, w = idx - (idx / 6) * 6;
        u32 v = lH32[r * 6 + w];
        store_sc_b32((u32*)((char*)hout + (size_t)(rg * 32 + r) * 1536 + cg * 24 + w * 4), v);
      }
      asm volatile("s_waitcnt vmcnt(0)" ::: "memory");
      if (ln == 0)
        store_sc_b32(flags + ((size_t)(layer * 514 + (t + 1)) * 2 + rg) * 64 + cg, 1u);
    }
  }

  // final states
  if (tid < 384) {
    int b = rg * 32 + cellb, j = cg * 12 + cellj;
    float* hf = out + HF_OFF;
    float* cf = out + HF_OFF + 98304;
    hf[(size_t)(layer * 64 + b) * 768 + j] = hKeep;
    cf[(size_t)(layer * 64 + b) * 768 + j] = cReg;
  }
}

extern "C" void kernel_launch(void* const* d_in, const int* in_sizes, int n_in,
                              void* d_out, int out_size, void* d_ws, size_t ws_size,
                              hipStream_t stream) {
  const float* x   = (const float*)d_in[0];
  const float* h0  = (const float*)d_in[1];
  const float* c0  = (const float*)d_in[2];
  const float* Wih = (const float*)d_in[3];
  const float* Whh = (const float*)d_in[4];
  const float* bih = (const float*)d_in[5];
  const float* bhh = (const float*)d_in[6];
  const int*   len = (const int*)d_in[7];
  float* out = (float*)d_out;

  u16*   Wr    = (u16*)d_ws;
  float* bcat  = (float*)((char*)d_ws + BCAT_OFF);
  u16*   hb0   = (u16*)((char*)d_ws + HB0_OFF);
  u16*   hb1   = (u16*)((char*)d_ws + HB1_OFF);
  u32*   flags = (u32*)((char*)d_ws + FLG_OFF);

  {
    const int units = 2 * 3072 * 192;
    prep_weights<<<(units + 255) / 256, 256, 0, stream>>>(Wih, Whh, Wr);
    const int n2 = 131584 + 98304 + 6144;
    prep_misc<<<(n2 + 255) / 256, 256, 0, stream>>>(h0, bih, bhh, hb0, hb1, bcat, flags);
  }

  void* args[] = { (void*)&x, (void*)&h0, (void*)&c0, (void*)&len,
                   (void*)&Wr, (void*)&bcat, (void*)&hb0, (void*)&hb1,
                   (void*)&flags, (void*)&out };
  hipLaunchCooperativeKernel((const void*)lstm_dataflow, dim3(256), dim3(512),
                             args, 0, stream);
}